// Round 1
// baseline (200.914 us; speedup 1.0000x reference)
//
#include <hip/hip_runtime.h>

// Problem constants
#define NB 4
#define SEQ 2048
#define CD 64            // head dim == model dim
#define NHEAD 8
#define BHN (NB * NHEAD) // 32
#define QKV_COLS 1536    // 3*H*CD
#define ROWS (NB * SEQ)  // 8192
#define HC 512           // H*CD

typedef float f32x4 __attribute__((ext_vector_type(4)));
typedef short s16x8 __attribute__((ext_vector_type(8)));
typedef unsigned short u16;

// round-to-nearest-even f32 -> bf16
__device__ __forceinline__ u16 f2bf(float x) {
  union { float f; unsigned u; } v; v.f = x;
  unsigned r = v.u + 0x7FFFu + ((v.u >> 16) & 1u);
  return (u16)(r >> 16);
}

__device__ __forceinline__ f32x4 mfma_bf16(s16x8 a, s16x8 b, f32x4 c) {
  return __builtin_amdgcn_mfma_f32_16x16x32_bf16(a, b, c, 0, 0, 0);
}

// ---------------------------------------------------------------------------
// Kernel 1: qkv = x @ Wqkv  (fp32 compute), write bf16:
//   Q [B,H,N,64]  scaled by 0.125*log2(e)   (folds qk_scale + exp2 conversion)
//   K [B,H,N,64]
//   Vt [B,H,64,N] (transposed so PV B-frags are contiguous)
// grid (3, 512), block 256; block = 16 rows x 512 cols (2 cols/thread)
// ---------------------------------------------------------------------------
__global__ void __launch_bounds__(256) qkv_kernel(
    const float* __restrict__ x, const float* __restrict__ W,
    u16* __restrict__ Q, u16* __restrict__ K, u16* __restrict__ Vt) {
  __shared__ __align__(16) float xs[16][64];
  const int t = threadIdx.x;
  const int r0 = blockIdx.y * 16;          // global row (= b*SEQ + n)
  const int c0 = blockIdx.x * 512 + t;     // first column

  ((float4*)xs)[t] = ((const float4*)(x + (size_t)r0 * CD))[t];
  __syncthreads();

  float acc0[16], acc1[16];
#pragma unroll
  for (int r = 0; r < 16; ++r) { acc0[r] = 0.f; acc1[r] = 0.f; }

  for (int k = 0; k < 64; k += 4) {
    float w0[4], w1[4];
#pragma unroll
    for (int j = 0; j < 4; ++j) {
      w0[j] = W[(size_t)(k + j) * QKV_COLS + c0];
      w1[j] = W[(size_t)(k + j) * QKV_COLS + c0 + 256];
    }
#pragma unroll
    for (int r = 0; r < 16; ++r) {
      float4 xv = *(const float4*)&xs[r][k];
      acc0[r] += xv.x * w0[0] + xv.y * w0[1] + xv.z * w0[2] + xv.w * w0[3];
      acc1[r] += xv.x * w1[0] + xv.y * w1[1] + xv.z * w1[2] + xv.w * w1[3];
    }
  }

  const int b = r0 >> 11;            // row / SEQ
  const int n0 = r0 & (SEQ - 1);
#pragma unroll
  for (int half = 0; half < 2; ++half) {
    const int c = c0 + half * 256;
    const int three = c >> 9;
    const int h = (c >> 6) & 7;
    const int cc = c & 63;
    if (three == 2) {
      // V: pack 16 consecutive n per thread -> two 16B stores
      union { u16 u[16]; int4 v[2]; } buf;
#pragma unroll
      for (int r = 0; r < 16; ++r) buf.u[r] = f2bf(half ? acc1[r] : acc0[r]);
      int4* dst = (int4*)(Vt + (((size_t)(b * NHEAD + h) * CD + cc) * SEQ + n0));
      dst[0] = buf.v[0];
      dst[1] = buf.v[1];
    } else {
      u16* dstp = (three == 0) ? Q : K;
      const float scl = (three == 0) ? 0.18033688011112042f : 1.0f; // 0.125*log2(e)
      u16* base = dstp + ((size_t)(b * NHEAD + h) * SEQ + n0) * CD + cc;
#pragma unroll
      for (int r = 0; r < 16; ++r)
        base[(size_t)r * CD] = f2bf((half ? acc1[r] : acc0[r]) * scl);
    }
  }
}

// ---------------------------------------------------------------------------
// Kernel 2: flash attention, bf16 MFMA 16x16x32, fixed-shift softmax
//   p = exp2(s' - 16*log2e)  with s' = (q.k)*0.125*log2e  (scale folded into Q)
//   row-sum l accumulated via extra MFMA against constant ones-column B-frag.
// grid (SEQ/64, B*H), block 256 (4 waves, each wave owns 16 q rows)
// ---------------------------------------------------------------------------
__global__ void __launch_bounds__(256) attn_kernel(
    const u16* __restrict__ Q, const u16* __restrict__ K,
    const u16* __restrict__ Vt, float* __restrict__ O) {
  __shared__ __align__(16) u16 Ks[32 * 72];      // [key][c], stride 72 (pad)
  __shared__ __align__(16) u16 Vs[64 * 32];      // [c][key], stride 32
  __shared__ __align__(16) u16 Ps[4][16 * 40];   // per-wave P [q][key], stride 40

  const int t = threadIdx.x;
  const int w = t >> 6;
  const int lane = t & 63;
  const int quad = lane >> 4;
  const int c16 = lane & 15;

  const int bh = blockIdx.y;
  const int q0 = blockIdx.x * 64 + w * 16;

  const u16* Qbh = Q + (size_t)bh * SEQ * CD;
  const u16* Kbh = K + (size_t)bh * SEQ * CD;
  const u16* Vbh = Vt + (size_t)bh * CD * SEQ;

  // Q A-fragments, kept in registers for the whole K loop
  const s16x8 qf0 = *(const s16x8*)(Qbh + (size_t)(q0 + c16) * CD + quad * 8);
  const s16x8 qf1 = *(const s16x8*)(Qbh + (size_t)(q0 + c16) * CD + 32 + quad * 8);

  // constant B-frag: ones in column 0 -> PV mfma accumulates row-sums of P
  s16x8 onesf;
  {
    const short o = (c16 == 0) ? (short)0x3F80 : (short)0; // bf16 1.0
#pragma unroll
    for (int j = 0; j < 8; ++j) onesf[j] = o;
  }

  f32x4 o0 = {0.f,0.f,0.f,0.f}, o1 = o0, o2 = o0, o3 = o0, osum = o0;

  const int skey = t >> 3, scg = (t & 7) * 8;  // K staging: [key][c]
  const int svc = t >> 2, svk = (t & 3) * 8;   // V staging: [c][key]

  for (int kt = 0; kt < SEQ; kt += 32) {
    __syncthreads();   // protect LDS reuse across waves
    *(int4*)&Ks[skey * 72 + scg] =
        *(const int4*)(Kbh + (size_t)(kt + skey) * CD + scg);
    *(int4*)&Vs[svc * 32 + svk] =
        *(const int4*)(Vbh + (size_t)svc * SEQ + kt + svk);
    __syncthreads();

    // S = Q . K^T  (two 16-key column tiles, 2 c-chunks each)
    f32x4 s0 = {0.f,0.f,0.f,0.f}, s1 = s0;
    s0 = mfma_bf16(qf0, *(const s16x8*)&Ks[c16 * 72 + quad * 8], s0);
    s0 = mfma_bf16(qf1, *(const s16x8*)&Ks[c16 * 72 + 32 + quad * 8], s0);
    s1 = mfma_bf16(qf0, *(const s16x8*)&Ks[(16 + c16) * 72 + quad * 8], s1);
    s1 = mfma_bf16(qf1, *(const s16x8*)&Ks[(16 + c16) * 72 + 32 + quad * 8], s1);

    // P = exp2(S - 16*log2e) -> bf16 -> LDS (C-layout write, A-layout read)
    u16* Pw = Ps[w];
#pragma unroll
    for (int i = 0; i < 4; ++i) {
      const float p0 = exp2f(s0[i] - 23.083120654223414f);
      const float p1 = exp2f(s1[i] - 23.083120654223414f);
      Pw[(quad * 4 + i) * 40 + c16] = f2bf(p0);
      Pw[(quad * 4 + i) * 40 + 16 + c16] = f2bf(p1);
    }

    const s16x8 pf = *(const s16x8*)&Pw[c16 * 40 + quad * 8];
    o0 = mfma_bf16(pf, *(const s16x8*)&Vs[c16 * 32 + quad * 8], o0);
    o1 = mfma_bf16(pf, *(const s16x8*)&Vs[(16 + c16) * 32 + quad * 8], o1);
    o2 = mfma_bf16(pf, *(const s16x8*)&Vs[(32 + c16) * 32 + quad * 8], o2);
    o3 = mfma_bf16(pf, *(const s16x8*)&Vs[(48 + c16) * 32 + quad * 8], o3);
    osum = mfma_bf16(pf, onesf, osum);
  }

  // finalize: divide by row-sum (col 0 of osum lives in lane quad*16)
  const int b = bh >> 3;
  const int h = bh & 7;
#pragma unroll
  for (int i = 0; i < 4; ++i) {
    const float l = __shfl(osum[i], lane & 48);
    const float inv = 1.0f / l;
    const int n = q0 + quad * 4 + i;
    float* dst = O + (size_t)(b * SEQ + n) * HC + h * CD;
    dst[c16]      = o0[i] * inv;
    dst[16 + c16] = o1[i] * inv;
    dst[32 + c16] = o2[i] * inv;
    dst[48 + c16] = o3[i] * inv;
  }
}

// ---------------------------------------------------------------------------
// Kernel 3: out = O @ Wproj + bproj  (fp32)
// grid (ROWS/16), block 256; thread = 1 col x 4 rows, O rows staged in LDS
// ---------------------------------------------------------------------------
__global__ void __launch_bounds__(256) proj_kernel(
    const float* __restrict__ O, const float* __restrict__ Wp,
    const float* __restrict__ bias, float* __restrict__ out) {
  __shared__ __align__(16) float Os[16 * 512];
  const int t = threadIdx.x;
  const int r0 = blockIdx.x * 16;

  const float4* src = (const float4*)(O + (size_t)r0 * HC);
  float4* dl = (float4*)Os;
#pragma unroll
  for (int i = 0; i < 8; ++i) dl[t + 256 * i] = src[t + 256 * i];
  __syncthreads();

  const int c = t & 63;
  const int rg = t >> 6;   // 0..3
  float acc[4] = {0.f, 0.f, 0.f, 0.f};
  for (int k = 0; k < HC; k += 4) {
    float wv[4];
#pragma unroll
    for (int j = 0; j < 4; ++j) wv[j] = Wp[(size_t)(k + j) * CD + c];
#pragma unroll
    for (int j = 0; j < 4; ++j) {
      float4 ov = *(const float4*)&Os[(rg * 4 + j) * HC + k];
      acc[j] += ov.x * wv[0] + ov.y * wv[1] + ov.z * wv[2] + ov.w * wv[3];
    }
  }
  const float bv = bias[c];
#pragma unroll
  for (int j = 0; j < 4; ++j)
    out[(size_t)(r0 + rg * 4 + j) * CD + c] = acc[j] + bv;
}

// ---------------------------------------------------------------------------
extern "C" void kernel_launch(void* const* d_in, const int* in_sizes, int n_in,
                              void* d_out, int out_size, void* d_ws, size_t ws_size,
                              hipStream_t stream) {
  (void)in_sizes; (void)n_in; (void)out_size; (void)ws_size;
  const float* x     = (const float*)d_in[0];
  const float* Wqkv  = (const float*)d_in[1];
  const float* Wproj = (const float*)d_in[2];
  const float* bproj = (const float*)d_in[3];
  float* out = (float*)d_out;

  // workspace: Q,K,Vt bf16 (8MB each) + O f32 (16MB) = 40MB
  u16* Qw = (u16*)d_ws;
  u16* Kw = Qw + (size_t)BHN * SEQ * CD;
  u16* Vw = Kw + (size_t)BHN * SEQ * CD;
  float* Ow = (float*)(Vw + (size_t)BHN * SEQ * CD);

  qkv_kernel<<<dim3(3, 512), 256, 0, stream>>>(x, Wqkv, Qw, Kw, Vw);
  attn_kernel<<<dim3(SEQ / 64, BHN), 256, 0, stream>>>(Qw, Kw, Vw, Ow);
  proj_kernel<<<dim3(ROWS / 16), 256, 0, stream>>>(Ow, Wproj, bproj, out);
}

// Round 2
// 165.859 us; speedup vs baseline: 1.2113x; 1.2113x over previous
//
#include <hip/hip_runtime.h>

// Problem constants
#define NB 4
#define SEQ 2048
#define CD 64            // head dim == model dim
#define NHEAD 8
#define BHN (NB * NHEAD) // 32
#define ROWS (NB * SEQ)  // 8192
#define HC 512           // H*CD

#define QSCALE 0.18033688011112042f   // 0.125 * log2(e)
#define SHIFT  23.083120654223414f    // 16 * log2(e)

typedef float f32x4 __attribute__((ext_vector_type(4)));
typedef short s16x8 __attribute__((ext_vector_type(8)));
typedef unsigned short u16;

__device__ __forceinline__ u16 f2bf(float x) {
  union { float f; unsigned u; } v; v.f = x;
  unsigned r = v.u + 0x7FFFu + ((v.u >> 16) & 1u);
  return (u16)(r >> 16);
}

__device__ __forceinline__ float fast_exp2(float x) {
#if __has_builtin(__builtin_amdgcn_exp2f)
  return __builtin_amdgcn_exp2f(x);
#else
  return exp2f(x);
#endif
}

__device__ __forceinline__ f32x4 mfma_bf16(s16x8 a, s16x8 b, f32x4 c) {
  return __builtin_amdgcn_mfma_f32_16x16x32_bf16(a, b, c, 0, 0, 0);
}

// ---------------------------------------------------------------------------
// Kernel 0: weight prep. WT[n][k] = bf16(Wqkv[k][n])  (1536 x 64)
//           WpT[c][k] = bf16(Wproj[k][c])             (64 x 512)
// grid 384 x 256 threads
// ---------------------------------------------------------------------------
__global__ void __launch_bounds__(256) prep_kernel(
    const float* __restrict__ Wqkv, const float* __restrict__ Wproj,
    u16* __restrict__ WT, u16* __restrict__ WpT) {
  const int idx = blockIdx.x * 256 + threadIdx.x;
  if (idx < 64 * 1536) {
    const int k = idx / 1536, n = idx % 1536;   // coalesced read
    WT[n * CD + k] = f2bf(Wqkv[idx]);
  }
  if (idx < 512 * 64) {
    const int k = idx >> 6, c = idx & 63;
    WpT[c * HC + k] = f2bf(Wproj[idx]);
  }
}

// ---------------------------------------------------------------------------
// Kernel 1: qkv via MFMA.  x [8192x64] f32 (converted inline), WT bf16.
// Writes Q (scaled by QSCALE), K, V all as [B,H,N,64] bf16.
// grid (128 rowblk, 4 colblk), block 256 = 4 waves; wave = 16 rows x 384 cols
// ---------------------------------------------------------------------------
__global__ void __launch_bounds__(256) qkv_kernel(
    const float* __restrict__ x, const u16* __restrict__ WT,
    u16* __restrict__ Q, u16* __restrict__ K, u16* __restrict__ V) {
  const int t = threadIdx.x;
  const int w = t >> 6, lane = t & 63, quad = lane >> 4, c16 = lane & 15;
  const int r0 = blockIdx.x * 64 + w * 16;
  const int c0 = blockIdx.y * 384;

  // A-fragments: x[r0+c16][kc*32 + quad*8 .. +7] converted to bf16
  s16x8 af[2];
#pragma unroll
  for (int kc = 0; kc < 2; ++kc) {
    const float* xp = x + (size_t)(r0 + c16) * CD + kc * 32 + quad * 8;
    float4 x0 = *(const float4*)xp;
    float4 x1 = *(const float4*)(xp + 4);
    union { u16 u[8]; s16x8 v; } tmp;
    tmp.u[0] = f2bf(x0.x); tmp.u[1] = f2bf(x0.y);
    tmp.u[2] = f2bf(x0.z); tmp.u[3] = f2bf(x0.w);
    tmp.u[4] = f2bf(x1.x); tmp.u[5] = f2bf(x1.y);
    tmp.u[6] = f2bf(x1.z); tmp.u[7] = f2bf(x1.w);
    af[kc] = tmp.v;
  }

  f32x4 acc[24];
#pragma unroll
  for (int nb = 0; nb < 24; ++nb) acc[nb] = (f32x4){0.f, 0.f, 0.f, 0.f};

#pragma unroll
  for (int nb = 0; nb < 24; ++nb) {
#pragma unroll
    for (int kc = 0; kc < 2; ++kc) {
      const s16x8 bf_ = *(const s16x8*)(WT + (size_t)(c0 + nb * 16 + c16) * CD +
                                        kc * 32 + quad * 8);
      acc[nb] = mfma_bf16(af[kc], bf_, acc[nb]);
    }
  }

#pragma unroll
  for (int nb = 0; nb < 24; ++nb) {
    const int cb = c0 + nb * 16;           // wave-uniform column base
    const int three = cb >> 9;
    const int h = (cb >> 6) & 7;
    const int ccb = cb & 63;
    u16* dstp = (three == 0) ? Q : ((three == 1) ? K : V);
    const float scl = (three == 0) ? QSCALE : 1.0f;
#pragma unroll
    for (int i = 0; i < 4; ++i) {
      const int r = r0 + quad * 4 + i;
      const int b = r >> 11, nn = r & (SEQ - 1);
      dstp[((size_t)(b * NHEAD + h) * SEQ + nn) * CD + ccb + c16] =
          f2bf(acc[nb][i] * scl);
    }
  }
}

// ---------------------------------------------------------------------------
// Kernel 2: V transpose per head: Vt[bh][c][n] = V[bh][n][c]
// grid (32 n-tiles, 32 bh), block 256; 64x64 tile via LDS
// ---------------------------------------------------------------------------
__global__ void __launch_bounds__(256) vtrans_kernel(
    const u16* __restrict__ V, u16* __restrict__ Vt) {
  __shared__ __align__(16) u16 T[64][72];
  const int t = threadIdx.x;
  const int bh = blockIdx.y;
  const int n0 = blockIdx.x * 64;
  const u16* src = V + (size_t)bh * SEQ * CD;
  const int r = t >> 3, cg = (t & 7) * 8;
  *(int4*)&T[r][cg]      = *(const int4*)(src + (size_t)(n0 + r) * CD + cg);
  *(int4*)&T[r + 32][cg] = *(const int4*)(src + (size_t)(n0 + r + 32) * CD + cg);
  __syncthreads();
  const int c = t >> 3, ng = (t & 7) * 8;
  u16* dst = Vt + (size_t)bh * CD * SEQ;
#pragma unroll
  for (int half = 0; half < 2; ++half) {
    const int cc = c + half * 32;
    union { u16 u[8]; int4 v; } buf;
#pragma unroll
    for (int j = 0; j < 8; ++j) buf.u[j] = T[ng + j][cc];
    *(int4*)(dst + (size_t)cc * SEQ + n0 + ng) = buf.v;
  }
}

// ---------------------------------------------------------------------------
// Kernel 3: flash attention. Wave = 32 q-rows, block = 4 waves = 128 q.
// K-tile 32. p = exp2(s - SHIFT), shift folded into MFMA C-init.
// Row-sums via ones-column MFMA. Output O bf16 [B,N,H*64].
// grid (16, 32)
// ---------------------------------------------------------------------------
__global__ void __launch_bounds__(256) attn_kernel(
    const u16* __restrict__ Q, const u16* __restrict__ K,
    const u16* __restrict__ Vt, u16* __restrict__ O) {
  __shared__ __align__(16) u16 Ks[32 * 72];     // [key][c] stride 72
  __shared__ __align__(16) u16 Vs[64 * 40];     // [c][key] stride 40 (pad fix)
  __shared__ __align__(16) u16 Ps[4][32 * 40];  // per-wave P [q][key] stride 40

  const int t = threadIdx.x;
  const int w = t >> 6, lane = t & 63, quad = lane >> 4, c16 = lane & 15;
  const int bh = blockIdx.y;
  const int q0 = blockIdx.x * 128 + w * 32;

  const u16* Qb = Q + (size_t)bh * SEQ * CD;
  const u16* Kb = K + (size_t)bh * SEQ * CD;
  const u16* Vb = Vt + (size_t)bh * CD * SEQ;

  s16x8 qf[2][2];
#pragma unroll
  for (int qb = 0; qb < 2; ++qb)
#pragma unroll
    for (int cc = 0; cc < 2; ++cc)
      qf[qb][cc] = *(const s16x8*)(Qb + (size_t)(q0 + qb * 16 + c16) * CD +
                                   cc * 32 + quad * 8);

  s16x8 onesf;
  {
    const short o = (c16 == 0) ? (short)0x3F80 : (short)0;
#pragma unroll
    for (int j = 0; j < 8; ++j) onesf[j] = o;
  }

  f32x4 o[2][4], osum[2];
#pragma unroll
  for (int qb = 0; qb < 2; ++qb) {
    osum[qb] = (f32x4){0.f, 0.f, 0.f, 0.f};
#pragma unroll
    for (int cb = 0; cb < 4; ++cb) o[qb][cb] = (f32x4){0.f, 0.f, 0.f, 0.f};
  }

  const int skey = t >> 3, scg = (t & 7) * 8;  // K staging
  const int svc = t >> 2, svk = (t & 3) * 8;   // V staging

  for (int kt = 0; kt < SEQ; kt += 32) {
    __syncthreads();
    *(int4*)&Ks[skey * 72 + scg] =
        *(const int4*)(Kb + (size_t)(kt + skey) * CD + scg);
    *(int4*)&Vs[svc * 40 + svk] =
        *(const int4*)(Vb + (size_t)svc * SEQ + kt + svk);
    __syncthreads();

    // fragment loads, shared across both q-blocks
    s16x8 kf[2][2], vf[4];
#pragma unroll
    for (int kb = 0; kb < 2; ++kb)
#pragma unroll
      for (int cc = 0; cc < 2; ++cc)
        kf[kb][cc] = *(const s16x8*)&Ks[(kb * 16 + c16) * 72 + cc * 32 + quad * 8];
#pragma unroll
    for (int cb = 0; cb < 4; ++cb)
      vf[cb] = *(const s16x8*)&Vs[(cb * 16 + c16) * 40 + quad * 8];

    u16* Pw = Ps[w];
#pragma unroll
    for (int qb = 0; qb < 2; ++qb) {
      f32x4 s0 = (f32x4){-SHIFT, -SHIFT, -SHIFT, -SHIFT};
      f32x4 s1 = s0;
      s0 = mfma_bf16(qf[qb][0], kf[0][0], s0);
      s0 = mfma_bf16(qf[qb][1], kf[0][1], s0);
      s1 = mfma_bf16(qf[qb][0], kf[1][0], s1);
      s1 = mfma_bf16(qf[qb][1], kf[1][1], s1);
#pragma unroll
      for (int i = 0; i < 4; ++i) {
        Pw[(qb * 16 + quad * 4 + i) * 40 + c16]      = f2bf(fast_exp2(s0[i]));
        Pw[(qb * 16 + quad * 4 + i) * 40 + 16 + c16] = f2bf(fast_exp2(s1[i]));
      }
    }
#pragma unroll
    for (int qb = 0; qb < 2; ++qb) {
      const s16x8 pf = *(const s16x8*)&Pw[(qb * 16 + c16) * 40 + quad * 8];
#pragma unroll
      for (int cb = 0; cb < 4; ++cb)
        o[qb][cb] = mfma_bf16(pf, vf[cb], o[qb][cb]);
      osum[qb] = mfma_bf16(pf, onesf, osum[qb]);
    }
  }

  const int b = bh >> 3, h = bh & 7;
#pragma unroll
  for (int qb = 0; qb < 2; ++qb) {
#pragma unroll
    for (int i = 0; i < 4; ++i) {
      const float l = __shfl(osum[qb][i], lane & 48);
      const float inv = 1.0f / l;
      const int q = q0 + qb * 16 + quad * 4 + i;
      u16* dst = O + ((size_t)(b * SEQ + q)) * HC + h * CD;
#pragma unroll
      for (int cb = 0; cb < 4; ++cb)
        dst[cb * 16 + c16] = f2bf(o[qb][cb][i] * inv);
    }
  }
}

// ---------------------------------------------------------------------------
// Kernel 4: proj via MFMA. O bf16 [8192x512] @ Wp bf16 -> out f32 [8192x64].
// Block 256 = 4 waves: (rowhalf, khalf); K split 2x256, LDS f32 reduce.
// grid 256
// ---------------------------------------------------------------------------
__global__ void __launch_bounds__(256) proj_kernel(
    const u16* __restrict__ O, const u16* __restrict__ WpT,
    const float* __restrict__ bias, float* __restrict__ out) {
  __shared__ __align__(16) float Cred[2 * 64 * 20];  // [rowhalf][col][row pad20]
  const int t = threadIdx.x;
  const int w = t >> 6, lane = t & 63, quad = lane >> 4, c16 = lane & 15;
  const int rowhalf = w & 1, khalf = w >> 1;
  const int r0 = blockIdx.x * 32 + rowhalf * 16;

  f32x4 acc[4];
#pragma unroll
  for (int nb = 0; nb < 4; ++nb) acc[nb] = (f32x4){0.f, 0.f, 0.f, 0.f};

#pragma unroll
  for (int kk = 0; kk < 8; ++kk) {
    const int kc = khalf * 8 + kk;
    const s16x8 af = *(const s16x8*)(O + (size_t)(r0 + c16) * HC +
                                     kc * 32 + quad * 8);
#pragma unroll
    for (int nb = 0; nb < 4; ++nb) {
      const s16x8 bf_ = *(const s16x8*)(WpT + (size_t)(nb * 16 + c16) * HC +
                                        kc * 32 + quad * 8);
      acc[nb] = mfma_bf16(af, bf_, acc[nb]);
    }
  }

  if (khalf == 1) {
#pragma unroll
    for (int nb = 0; nb < 4; ++nb)
      *(f32x4*)&Cred[(rowhalf * 64 + nb * 16 + c16) * 20 + quad * 4] = acc[nb];
  }
  __syncthreads();
  if (khalf == 0) {
#pragma unroll
    for (int nb = 0; nb < 4; ++nb) {
      const f32x4 other =
          *(const f32x4*)&Cred[(rowhalf * 64 + nb * 16 + c16) * 20 + quad * 4];
      const float bv = bias[nb * 16 + c16];
#pragma unroll
      for (int i = 0; i < 4; ++i)
        out[(size_t)(r0 + quad * 4 + i) * CD + nb * 16 + c16] =
            acc[nb][i] + other[i] + bv;
    }
  }
}

// ---------------------------------------------------------------------------
extern "C" void kernel_launch(void* const* d_in, const int* in_sizes, int n_in,
                              void* d_out, int out_size, void* d_ws, size_t ws_size,
                              hipStream_t stream) {
  (void)in_sizes; (void)n_in; (void)out_size; (void)ws_size;
  const float* x     = (const float*)d_in[0];
  const float* Wqkv  = (const float*)d_in[1];
  const float* Wproj = (const float*)d_in[2];
  const float* bproj = (const float*)d_in[3];
  float* out = (float*)d_out;

  // workspace layout (u16 units):
  u16* WT  = (u16*)d_ws;                      // 1536*64
  u16* WpT = WT + 1536 * CD;                  // 64*512
  u16* Qw  = WpT + CD * HC;                   // 32*2048*64
  u16* Kw  = Qw + (size_t)BHN * SEQ * CD;
  u16* Vw  = Kw + (size_t)BHN * SEQ * CD;     // V, dead after vtrans
  u16* Vtw = Vw + (size_t)BHN * SEQ * CD;
  u16* Ow  = Vw;                              // O bf16 aliases V (same size)

  prep_kernel<<<384, 256, 0, stream>>>(Wqkv, Wproj, WT, WpT);
  qkv_kernel<<<dim3(128, 4), 256, 0, stream>>>(x, WT, Qw, Kw, Vw);
  vtrans_kernel<<<dim3(32, 32), 256, 0, stream>>>(Vw, Vtw);
  attn_kernel<<<dim3(16, 32), 256, 0, stream>>>(Qw, Kw, Vtw, Ow);
  proj_kernel<<<256, 256, 0, stream>>>(Ow, WpT, bproj, out);
}